// Round 5
// baseline (647.569 us; speedup 1.0000x reference)
//
#include <hip/hip_runtime.h>
#include <cstdint>
#include <cstddef>

// Problem constants
#define BB 32
#define SS 2048
#define DD 1024
#define MM (BB * SS)   // 65536 rows of the big GEMM

typedef __bf16 bf16_t;
typedef __bf16 bf16x4 __attribute__((ext_vector_type(4)));
typedef __bf16 bf16x8 __attribute__((ext_vector_type(8)));
typedef float  f32x4  __attribute__((ext_vector_type(4)));

typedef __attribute__((address_space(1))) unsigned int gu32;
typedef __attribute__((address_space(3))) unsigned int lu32;

__device__ __forceinline__ void async_copy16(const void* g, void* l) {
  __builtin_amdgcn_global_load_lds((gu32*)g, (lu32*)l, 16, 0, 0);
}

// ---------------------------------------------------------------------------
// Kernel 1+2 merged: blocks 0..255 transpose/convert W1_enc -> W1T (bf16);
// blocks 256..511 compute dec_proj[b][u] = h_dec[b,:]@W1_dec[:,u] + b1[u].
// ---------------------------------------------------------------------------
__global__ __launch_bounds__(256) void prep_kernel(
    const float* __restrict__ W1, const float* __restrict__ hDec,
    const float* __restrict__ b1, bf16_t* __restrict__ W1T,
    float* __restrict__ dp) {
  __shared__ float tile[64][65];   // w1t half
  __shared__ float sred[256];      // dec_proj half
  if (blockIdx.x < 256) {
    const int bk = (blockIdx.x & 15) * 64;   // k tile origin
    const int bn = (blockIdx.x >> 4) * 64;   // n tile origin
    const int tx = threadIdx.x & 63;
    const int ty = threadIdx.x >> 6;         // 0..3
#pragma unroll
    for (int i = 0; i < 16; ++i) {
      const int kr = i * 4 + ty;
      tile[kr][tx] = W1[(size_t)(bk + kr) * 1024 + bn + tx];
    }
    __syncthreads();
#pragma unroll
    for (int i = 0; i < 16; ++i) {
      const int nr = i * 4 + ty;
      W1T[(size_t)(bn + nr) * 1024 + bk + tx] = (bf16_t)tile[tx][nr];
    }
  } else {
    const int bidx = blockIdx.x - 256;
    const int b  = bidx >> 3;
    const int uc = bidx & 7;
    const int t  = threadIdx.x;
    const int u  = uc * 128 + (t & 127);
    const int kh = t >> 7;
    const float* wd = W1 + (size_t)1024 * 1024 + u;   // W1_dec rows 1024..2047
    const float* hd = hDec + b * 1024 + kh * 512;
    float acc = 0.f;
#pragma unroll 4
    for (int k = 0; k < 512; ++k)
      acc += hd[k] * wd[(size_t)(kh * 512 + k) * 1024];
    sred[t] = acc;
    __syncthreads();
    if (t < 128) dp[b * 1024 + u] = sred[t] + sred[t + 128] + b1[u];
  }
}

// ---------------------------------------------------------------------------
// Kernel 3 v6: fused bf16 MFMA GEMM + tanh + W2 row-reduction -> e2 partials.
// vs v5 (198us, MfmaUtil 30.5, VALU 34.6, ~35% idle): K-loop hand-unrolled
// x2 with static buffer indices + peeled tail (removes per-iter pointer
// updates/branches), s_setprio(1) around each ds_read+MFMA cluster (the two
// resident blocks per CU have role diversity: one cvt-staging while the
// other MFMAs -> priority lets the MFMA block win issue slots).
// Dependency-verified wait structure (per wave, in-order vmem queue):
//   entering half t: in-flight [B(t) (older), A(t)]. cvt waits A(t) regs ->
//   drains B(t) too. bar#2 needs only lgkmcnt(0). B(t+1)/A(t+1) issued
//   after cvt stay in flight across both barriers (counted-wait discipline:
//   vmcnt never forced to 0 in the main body; tail half uses vmcnt(0)).
// tile 128x256, 512 thr / 8 waves (2x4), per-wave 64x64, BK=64, LDS 80KB,
// 2 blocks/CU (128-unified-reg cliff: compiler fits 64+64acc exactly).
// grid = 2048 = 512 m-tiles x 4 n-blocks, XCD-swizzled (4 n-blocks of one
// m-tile on one XCD -> A slab HBM-read once, L2-served 3x).
// ---------------------------------------------------------------------------
__global__ __launch_bounds__(512, 4) void fused_gemm_v6(
    const float* __restrict__ hEnc, const bf16_t* __restrict__ W1T,
    const float* __restrict__ dp, const float* __restrict__ W2,
    float* __restrict__ e2p) {
  __shared__ bf16_t sA[128 * 64];        // 16KB: 2 planes x 8KB (128 rows)
  __shared__ bf16_t sB[2][256 * 64];     // 2 bufs x 32KB (256 rows, 2 planes)

  const int tid  = threadIdx.x;
  const int lane = tid & 63;
  const int wv   = tid >> 6;             // 0..7
  const int wm   = wv >> 2;              // 0..1  (m-half)
  const int wn   = wv & 3;               // 0..3  (n-quarter)

  const int bid   = blockIdx.x;
  const int mtile = ((bid >> 5) << 3) | (bid & 7);  // [0,512)
  const int nblk  = (bid >> 3) & 3;                 // [0,4)
  const int m0    = mtile * 128;
  const int n0    = nblk * 256;
  const int b     = m0 >> 11;                       // 2048 rows per batch elem

  const int col = lane & 15;
  const int q   = lane >> 4;
  const int sw  = q ^ ((col >> 1) & 3);             // XOR 16B-chunk swizzle

  f32x4 acc[4][4];
#pragma unroll
  for (int mi = 0; mi < 4; ++mi)
#pragma unroll
    for (int ni = 0; ni < 4; ++ni)
      acc[mi][ni] = (f32x4){0.f, 0.f, 0.f, 0.f};

  char* sAc = (char*)sA;
  char* sBc = (char*)&sB[0][0];

  // B async staging: wave wv fills slabs s0,s1 (16 rows each) of the 256-row
  // tile in each plane; LDS dest = base + lane*16 (wave-uniform base).
  const int lrow = lane >> 2;
  const int lc   = (lane & 3) ^ ((lane >> 3) & 3);
  const int s0   = wv * 2, s1 = wv * 2 + 1;
  const bf16_t* bG0 = W1T + (size_t)(n0 + s0 * 16 + lrow) * 1024 + lc * 8;
  const bf16_t* bG1 = W1T + (size_t)(n0 + s1 * 16 + lrow) * 1024 + lc * 8;

  // A fp32 reg staging: thread -> (rows frow, frow+64; float4 chunk fc).
  const int frow = tid >> 3;          // 0..63
  const int fc   = tid & 7;           // 0..7
  const float* aG = hEnc + (size_t)(m0 + frow) * 1024 + fc * 4;
  // v1/v4-proven write offset: 8B granularity, XOR chunk swizzle = read side.
  const unsigned wBase = (unsigned)(frow * 64 +
      (((fc >> 1) ^ ((frow >> 1) & 3)) << 4) + (fc & 1) * 8);

  const unsigned a_rd = (unsigned)((wm * 64 + col) * 64 + sw * 16);
  const unsigned b_rd = (unsigned)((wn * 64 + col) * 64 + sw * 16);

  float4 ar[2][2];   // [i = row-group (frow, frow+64)][pl = k-half]

#define STAGE_B(kk, bufc) do { char* nb = sBc + (bufc) * 32768;     \
    async_copy16(bG0 + (kk),      nb + s0 * 1024);                  \
    async_copy16(bG1 + (kk),      nb + s1 * 1024);                  \
    async_copy16(bG0 + (kk) + 32, nb + 16384 + s0 * 1024);          \
    async_copy16(bG1 + (kk) + 32, nb + 16384 + s1 * 1024); } while (0)

#define LOAD_A(kk) do {                                             \
    _Pragma("unroll")                                               \
    for (int i = 0; i < 2; ++i) {                                   \
      ar[i][0] = *(const float4*)(aG + (kk) + (size_t)i * 65536);   \
      ar[i][1] = *(const float4*)(aG + (kk) + 32 + (size_t)i * 65536); \
    } } while (0)

#define CVT_WRITE_A() do {                                          \
    _Pragma("unroll")                                               \
    for (int i = 0; i < 2; ++i) {                                   \
      _Pragma("unroll")                                             \
      for (int pl = 0; pl < 2; ++pl) {                              \
        const float4 v = ar[i][pl];                                 \
        bf16x4 a4;                                                  \
        a4[0] = (bf16_t)v.x; a4[1] = (bf16_t)v.y;                   \
        a4[2] = (bf16_t)v.z; a4[3] = (bf16_t)v.w;                   \
        *(bf16x4*)(sAc + pl * 8192 + wBase + i * 4096) = a4;        \
      } } } while (0)

#define MFMA_PHASE(bufc) do {                                       \
    const char* sBr = sBc + (bufc) * 32768;                         \
    __builtin_amdgcn_s_setprio(1);                                  \
    _Pragma("unroll")                                               \
    for (int pl = 0; pl < 2; ++pl) {                                \
      bf16x8 af[4], bf[4];                                          \
      _Pragma("unroll")                                             \
      for (int mi = 0; mi < 4; ++mi)                                \
        af[mi] = *(const bf16x8*)(sAc + pl * 8192 + a_rd + mi * 1024); \
      _Pragma("unroll")                                             \
      for (int ni = 0; ni < 4; ++ni)                                \
        bf[ni] = *(const bf16x8*)(sBr + pl * 16384 + b_rd + ni * 1024); \
      _Pragma("unroll")                                             \
      for (int mi = 0; mi < 4; ++mi)                                \
        _Pragma("unroll")                                           \
        for (int ni = 0; ni < 4; ++ni)                              \
          acc[mi][ni] = __builtin_amdgcn_mfma_f32_16x16x32_bf16(af[mi], bf[ni], acc[mi][ni], 0, 0, 0); \
    }                                                               \
    __builtin_amdgcn_s_setprio(0); } while (0)

  // One K-step: consume buf cc at k=kcur; prefetch B(k+64)->cc^1, A(k+64).
#define GEMM_HALF(kcur, cc) do {                                    \
    STAGE_B((kcur) + 64, (cc) ^ 1);                                 \
    CVT_WRITE_A();              /* waits A(kcur) regs; drains B(kcur) */ \
    asm volatile("s_waitcnt lgkmcnt(0)" ::: "memory");              \
    __builtin_amdgcn_sched_barrier(0);                              \
    __builtin_amdgcn_s_barrier();                                   \
    __builtin_amdgcn_sched_barrier(0);                              \
    LOAD_A((kcur) + 64);                                            \
    MFMA_PHASE(cc);                                                 \
    __builtin_amdgcn_s_barrier();                                   \
    __builtin_amdgcn_sched_barrier(0);                              \
  } while (0)

  // prologue: B(0) -> buf0, A(0) -> regs
  STAGE_B(0, 0);
  LOAD_A(0);

#pragma unroll 1
  for (int tt = 0; tt < 7; ++tt) {          // t = 0..13
    const int k0 = tt * 128;
    GEMM_HALF(k0, 0);
    GEMM_HALF(k0 + 64, 1);
  }
  // t = 14: full half (stages B(15), loads A(15))
  GEMM_HALF(896, 0);
  // t = 15 tail: no prefetch; belt-and-suspenders vmcnt(0)
  CVT_WRITE_A();
  asm volatile("s_waitcnt lgkmcnt(0) vmcnt(0)" ::: "memory");
  __builtin_amdgcn_sched_barrier(0);
  __builtin_amdgcn_s_barrier();
  __builtin_amdgcn_sched_barrier(0);
  MFMA_PHASE(1);

#undef GEMM_HALF
#undef MFMA_PHASE
#undef CVT_WRITE_A
#undef STAGE_B
#undef LOAD_A

  // Epilogue: rs = sum_n tanh(acc + dp[n]) * W2[n]; butterfly over 16 cols;
  // plain float4 store to partial slot (nblk*4 + wn) -- no atomics.
  float rs[4][4];
#pragma unroll
  for (int mi = 0; mi < 4; ++mi)
#pragma unroll
    for (int r = 0; r < 4; ++r) rs[mi][r] = 0.f;

  const float* dpb = dp + b * 1024 + n0 + wn * 64 + col;
  const float* w2b = W2 + n0 + wn * 64 + col;
#pragma unroll
  for (int ni = 0; ni < 4; ++ni) {
    const float dpn = dpb[ni * 16];
    const float w2n = w2b[ni * 16];
#pragma unroll
    for (int mi = 0; mi < 4; ++mi)
#pragma unroll
      for (int r = 0; r < 4; ++r) {
        const float x = acc[mi][ni][r] + dpn;
        const float e = __expf(2.f * x);       // tanh(x) = 1 - 2/(e^{2x}+1)
        const float th = 1.f - 2.f / (e + 1.f);
        rs[mi][r] += th * w2n;
      }
  }
#pragma unroll
  for (int off = 1; off < 16; off <<= 1)
#pragma unroll
    for (int mi = 0; mi < 4; ++mi)
#pragma unroll
      for (int r = 0; r < 4; ++r)
        rs[mi][r] += __shfl_xor(rs[mi][r], off, 64);
  if (col == 0) {
    float* dst = e2p + (size_t)(nblk * 4 + wn) * MM + m0 + wm * 64 + q * 4;
#pragma unroll
    for (int mi = 0; mi < 4; ++mi) {
      f32x4 o4 = {rs[mi][0], rs[mi][1], rs[mi][2], rs[mi][3]};
      *(f32x4*)(dst + mi * 16) = o4;
    }
  }
}

// ---------------------------------------------------------------------------
// Kernel 4: per-b softmax over S of relu(sum of 16 e2 partials + b2).
// ---------------------------------------------------------------------------
__global__ __launch_bounds__(256) void softmax_v2(
    const float* __restrict__ e2p, const float* __restrict__ b2,
    float* __restrict__ attn) {
  const int b = blockIdx.x;
  const int t = threadIdx.x;
  __shared__ float sred[4];
  const float b2v = b2[0];
  float v[8];
  float lmax = 0.f;  // relu output >= 0
#pragma unroll
  for (int i = 0; i < 8; ++i) {
    const float* p = e2p + b * 2048 + i * 256 + t;
    float s = 0.f;
#pragma unroll
    for (int ps = 0; ps < 16; ++ps) s += p[(size_t)ps * MM];
    v[i] = fmaxf(s + b2v, 0.f);
    lmax = fmaxf(lmax, v[i]);
  }
#pragma unroll
  for (int off = 1; off < 64; off <<= 1) lmax = fmaxf(lmax, __shfl_xor(lmax, off, 64));
  const int wv = t >> 6;
  const int lane = t & 63;
  if (lane == 0) sred[wv] = lmax;
  __syncthreads();
  const float bmax = fmaxf(fmaxf(sred[0], sred[1]), fmaxf(sred[2], sred[3]));
  __syncthreads();
  float ev[8];
  float lsum = 0.f;
#pragma unroll
  for (int i = 0; i < 8; ++i) { ev[i] = __expf(v[i] - bmax); lsum += ev[i]; }
#pragma unroll
  for (int off = 1; off < 64; off <<= 1) lsum += __shfl_xor(lsum, off, 64);
  if (lane == 0) sred[wv] = lsum;
  __syncthreads();
  const float inv = 1.f / (sred[0] + sred[1] + sred[2] + sred[3]);
#pragma unroll
  for (int i = 0; i < 8; ++i) attn[b * 2048 + i * 256 + t] = ev[i] * inv;
}

// ---------------------------------------------------------------------------
// Kernel 5 v3: context partials from fp32 hEnc, no atomics.
// grid = 32 b x 8 s-chunks(256); thread covers d = t*4..t*4+3.
// Writes ctxp[8][32][1024].
// ---------------------------------------------------------------------------
__global__ __launch_bounds__(256) void context_v3(
    const float* __restrict__ hEnc, const float* __restrict__ attn,
    float* __restrict__ ctxp) {
  const int b = blockIdx.x >> 3;
  const int cks = blockIdx.x & 7;
  const int t = threadIdx.x;
  __shared__ float w[256];
  w[t] = attn[b * 2048 + cks * 256 + t];
  __syncthreads();
  float ax = 0.f, ay = 0.f, az = 0.f, aw = 0.f;
  const float* base = hEnc + ((size_t)b * 2048 + cks * 256) * 1024 + t * 4;
#pragma unroll 8
  for (int s = 0; s < 256; ++s) {
    const float4 h4 = *(const float4*)(base + (size_t)s * 1024);
    const float ws = w[s];
    ax += ws * h4.x; ay += ws * h4.y; az += ws * h4.z; aw += ws * h4.w;
  }
  f32x4 o4 = {ax, ay, az, aw};
  *(f32x4*)(ctxp + (size_t)cks * 32768 + b * 1024 + t * 4) = o4;
}

// ---------------------------------------------------------------------------
// Kernel 6 v3: reduce 8 context partials -> out[0..32768). 32 x 256 thr.
// ---------------------------------------------------------------------------
__global__ __launch_bounds__(256) void ctx_reduce8(
    const float* __restrict__ ctxp, float* __restrict__ ctx) {
  const int idx = blockIdx.x * 256 + threadIdx.x;  // [0, 8192) float4 groups
  f32x4 s = {0.f, 0.f, 0.f, 0.f};
#pragma unroll
  for (int p = 0; p < 8; ++p)
    s += *(const f32x4*)(ctxp + (size_t)p * 32768 + (size_t)idx * 4);
  *(f32x4*)(ctx + (size_t)idx * 4) = s;
}

// ---------------------------------------------------------------------------
extern "C" void kernel_launch(void* const* d_in, const int* in_sizes, int n_in,
                              void* d_out, int out_size, void* d_ws, size_t ws_size,
                              hipStream_t stream) {
  const float* hEnc = (const float*)d_in[0];  // (32,2048,1024) fp32
  const float* hDec = (const float*)d_in[1];  // (32,1024) fp32
  const float* W1   = (const float*)d_in[2];  // (2048,1024) fp32
  const float* b1   = (const float*)d_in[3];  // (1024,) fp32
  const float* W2   = (const float*)d_in[4];  // (1024,1) fp32
  const float* b2   = (const float*)d_in[5];  // (1,) fp32
  float* out = (float*)d_out;                 // [0,32768): context; [32768,98304): attn

  // workspace (total ~7.4MB; overhead model: fixed ~300us harness + ws-poison
  // at ~2.2TB/s, so small ws is mandatory):
  //   W1T bf16 2MB | dp 128KB | e2p 4MB | ctxp 1MB
  char* ws = (char*)d_ws;
  bf16_t* W1T  = (bf16_t*)ws;
  float*  dp   = (float*)(ws + 2u * 1024 * 1024);
  float*  e2p  = (float*)(ws + 2u * 1024 * 1024 + 128u * 1024);
  float*  ctxp = (float*)(ws + 6u * 1024 * 1024 + 128u * 1024);

  prep_kernel<<<512, 256, 0, stream>>>(W1, hDec, b1, W1T, dp);
  fused_gemm_v6<<<2048, 512, 0, stream>>>(hEnc, W1T, dp, W2, e2p);
  softmax_v2<<<32, 256, 0, stream>>>(e2p, b2, out + 32768);
  context_v3<<<256, 256, 0, stream>>>(hEnc, out + 32768, ctxp);
  ctx_reduce8<<<32, 256, 0, stream>>>(ctxp, out);
}